// Round 2
// baseline (37.291 us; speedup 1.0000x reference)
//
#include <hip/hip_runtime.h>
#include <stdint.h>

// PropNet cost-volume via bf16 MFMA, with y pre-transposed to bf16 by a
// streaming prepass (kills the per-block channel-gather + pack).
// N=2, C=256, H=W=96, max_distance=4 (window 9x9), num_class=124.
#define Nn 2
#define Cc 256
#define Hh 96
#define Ww 96
#define HW (Hh * Ww)
#define MD 4
#define NC 124
#define TH 4                    // dest tile rows
#define TWD 8                   // dest tile cols
#define NQ (TH * TWD)           // 32 dest pixels (MFMA M)
#define SH (TH + 2 * MD)        // 12 window rows
#define SWD (TWD + 2 * MD)      // 16 window cols
#define NS (SH * SWD)           // 192 src pixels (MFMA N)
#define BLK 256                 // 4 waves
#define NBW (Ww / TWD)          // 12
#define NBH (Hh / TH)           // 24
#define NBLK (Nn * NBH * NBW)   // 576 blocks (divisible by 8)
#define YROW 64                 // bytes per pixel row in a chunk (32 ch * 2B)
#define XOFF (NS * YROW)        // 12288: x region offset inside a buffer
#define BUFSZ (XOFF + NQ * YROW) // 14336 bytes per buffer
#define TBL (NQ * NC)           // 3968 table entries (15872B <= 2*BUFSZ)
#define CQ 32                   // 8-channel groups in C=256

// prepass geometry
#define PSTRIP 16
#define PPIX (HW / PSTRIP)      // 576 pixels per strip
#define PBLK (Nn * CQ * PSTRIP) // 1024 blocks

// workspace layout: yT (bf16, [n][cq][pix][8ch] = uint4 per (pix,cq)), then y2
#define YT_U4   ((size_t)Nn * CQ * HW)   // 589824 uint4 = 9.44 MB
#define Y2_OFF  (YT_U4 * 16)
#define Y2_BYTES ((size_t)Nn * HW * 4)   // 73728 B

typedef short short8 __attribute__((ext_vector_type(8)));
typedef float f32x4 __attribute__((ext_vector_type(4)));

// Monotone float -> uint mapping so unsigned min == float min.
__device__ __forceinline__ unsigned fmap(float f) {
    unsigned b = __float_as_uint(f);
    return (b & 0x80000000u) ? ~b : (b | 0x80000000u);
}
__device__ __forceinline__ float funmap(unsigned u) {
    unsigned b = (u & 0x80000000u) ? (u & 0x7fffffffu) : ~u;
    return __uint_as_float(b);
}
// XOR-swizzled byte offset of 16B ch-slot `slot` in pixel-row `row`.
// Depends only on (row&15): slot position = slot ^ ((row&15)>>1 & 3).
__device__ __forceinline__ int swz(int row, int slot) {
    return row * YROW + ((slot ^ ((row >> 1) & 3)) << 4);
}

// ---------------- prepass: y fp32 NCHW -> bf16 [n][cq][pix][8], y2 per pixel --
__global__ __launch_bounds__(256) void prep_y(
    const float* __restrict__ y, uint4* __restrict__ yT, float* __restrict__ y2g)
{
    __shared__ float tile[8 * PPIX];   // 18.4 KB
    const int t = threadIdx.x;
    const int bid = blockIdx.x;
    const int n = bid / (CQ * PSTRIP);
    const int r = bid - n * (CQ * PSTRIP);
    const int cq = r / PSTRIP;
    const int strip = r - cq * PSTRIP;
    const size_t pbase = (size_t)strip * PPIX;
    const float* src = y + ((size_t)n * Cc + cq * 8) * HW + pbase;

    // coalesced float4 loads: 8 ch x 144 f4 = 1152 tasks
    for (int task = t; task < 8 * (PPIX / 4); task += 256) {
        const int ch = task / (PPIX / 4);
        const int p4 = task - ch * (PPIX / 4);
        const float4 v = *(const float4*)(src + (size_t)ch * HW + p4 * 4);
        *(float4*)&tile[ch * PPIX + p4 * 4] = v;
    }
    __syncthreads();

    uint4* dst = yT + ((size_t)n * CQ + cq) * HW + pbase;
    float* y2p = y2g + (size_t)n * HW + pbase;
    for (int p = t; p < PPIX; p += 256) {
        float v[8]; float sq = 0.f;
#pragma unroll
        for (int c = 0; c < 8; ++c) { v[c] = tile[c * PPIX + p]; sq = fmaf(v[c], v[c], sq); }
        uint4 pk;
        pk.x = (__float_as_uint(v[0]) >> 16) | (__float_as_uint(v[1]) & 0xffff0000u);
        pk.y = (__float_as_uint(v[2]) >> 16) | (__float_as_uint(v[3]) & 0xffff0000u);
        pk.z = (__float_as_uint(v[4]) >> 16) | (__float_as_uint(v[5]) & 0xffff0000u);
        pk.w = (__float_as_uint(v[6]) >> 16) | (__float_as_uint(v[7]) & 0xffff0000u);
        dst[p] = pk;
        atomicAdd(&y2p[p], sq);
    }
}

// ---------------- main kernel --------------------------------------------
__global__ __launch_bounds__(BLK) void propnet_mfma(
    const float* __restrict__ x, const uint4* __restrict__ yT,
    const float* __restrict__ y2g, const int* __restrict__ labels,
    float* __restrict__ out)
{
    __shared__ __align__(16) unsigned char sbuf[2][BUFSZ];  // double-buffered staging
    __shared__ float y2s[NS];
    __shared__ float x2s[NQ];
    __shared__ int   labs[NS];
    unsigned* table = (unsigned*)&sbuf[0][0];  // aliased after the K-loop

    const int t = threadIdx.x;

    // XCD-aware bijective swizzle: contiguous 72-block chunk per XCD.
    const int orig = blockIdx.x;
    const int lin  = (orig & 7) * (NBLK / 8) + (orig >> 3);
    const int n    = lin / (NBH * NBW);
    const int rem  = lin - n * (NBH * NBW);
    const int h0   = (rem / NBW) * TH;
    const int w0   = (rem % NBW) * TWD;

    if (t < NS) {
        const int sr = t >> 4, sc = t & 15;
        const int gh = h0 - MD + sr, gw = w0 - MD + sc;
        const bool ok = (gh >= 0) && (gh < Hh) && (gw >= 0) && (gw < Ww);
        labs[t] = ok ? labels[(size_t)n * HW + gh * Ww + gw] : -1;  // -1: excluded
        y2s[t]  = ok ? y2g[(size_t)n * HW + gh * Ww + gw] : 0.f;
    }
    if (t < NQ) x2s[t] = 0.f;

    const int lane = t & 63;
    const int wid  = t >> 6;

    // ---- y staging via global_load_lds: 3 insts/wave/chunk; linear LDS dest,
    // swizzle realized by permuting the per-lane GLOBAL source (rule #21).
    size_t ysrc[3]; int yl[3];
    {
        const int sc4 = lane >> 2;                 // col within 16-pixel group
        const int pos = lane & 3;                  // 16B position in pixel row
        const int cqw = pos ^ ((sc4 >> 1) & 3);    // ch-slot stored at this pos
#pragma unroll
        for (int i = 0; i < 3; ++i) {
            const int g  = wid * 3 + i;            // window row 0..11
            const int gh = min(max(h0 - MD + g, 0), Hh - 1);   // clamp; OOB excluded by labs
            const int gw = min(max(w0 - MD + sc4, 0), Ww - 1);
            ysrc[i] = (size_t)cqw * HW + (size_t)gh * Ww + gw;
            yl[i]   = g * 1024;                    // 16 rows * 64B
        }
    }
    const uint4* yTn = yT + (size_t)n * CQ * HW;
    auto stageY = [&](int b, int c) {
        const uint4* base = yTn + (size_t)(c * 4) * HW;
#pragma unroll
        for (int i = 0; i < 3; ++i) {
            const void* gp = (const void*)(base + ysrc[i]);
            void*       lp = (void*)(sbuf[b] + yl[i]);
            __builtin_amdgcn_global_load_lds(
                (const __attribute__((address_space(1))) unsigned int*)gp,
                (__attribute__((address_space(3))) unsigned int*)lp, 16, 0, 0);
        }
    };

    // ---- x path: reg-staged fp32 (read once, no overlap tax); T14 split.
    const bool xw = (t < 128);
    const float* xptr = x; int xoffw = 0, xpix = 0;
    if (xw) {
        xpix = t & 31;
        const int grp = t >> 5;
        const int qr = xpix >> 3, qc = xpix & 7;
        xptr = x + ((size_t)n * Cc + grp * 8) * HW + (size_t)(h0 + qr) * Ww + (w0 + qc);
        xoffw = XOFF + swz(xpix, grp);
    }
    float xsq = 0.f;
    float xv[8];
    auto xload = [&](int c) {
        if (!xw) return;
        const float* p = xptr + (size_t)(c * 32) * HW;
#pragma unroll
        for (int j = 0; j < 8; ++j) xv[j] = p[(size_t)j * HW];
    };
    auto xwrite = [&](int b) {
        if (!xw) return;
        unsigned pk[4];
#pragma unroll
        for (int j = 0; j < 4; ++j) {
            xsq = fmaf(xv[2*j],   xv[2*j],   xsq);
            xsq = fmaf(xv[2*j+1], xv[2*j+1], xsq);
            pk[j] = (__float_as_uint(xv[2*j]) >> 16) |
                    (__float_as_uint(xv[2*j+1]) & 0xffff0000u);
        }
        *(uint4*)(sbuf[b] + xoffw) = make_uint4(pk[0], pk[1], pk[2], pk[3]);
    };

    // ---- MFMA fragments ----
    const int l15 = lane & 15;
    const int lg  = lane >> 4;        // 8-ch k-slot
    int aoff[2], boff[3];
#pragma unroll
    for (int mf = 0; mf < 2; ++mf) aoff[mf] = XOFF + swz(mf * 16 + l15, lg);
#pragma unroll
    for (int nf = 0; nf < 3; ++nf) boff[nf] = swz(wid * 48 + nf * 16 + l15, lg);

    f32x4 acc[2][3];
#pragma unroll
    for (int mf = 0; mf < 2; ++mf)
#pragma unroll
        for (int nf = 0; nf < 3; ++nf)
            acc[mf][nf] = (f32x4){0.f, 0.f, 0.f, 0.f};

    auto compute = [&](const unsigned char* bb) {
        short8 a[2], b[3];
#pragma unroll
        for (int mf = 0; mf < 2; ++mf) a[mf] = *(const short8*)(bb + aoff[mf]);
#pragma unroll
        for (int nf = 0; nf < 3; ++nf) b[nf] = *(const short8*)(bb + boff[nf]);
#pragma unroll
        for (int mf = 0; mf < 2; ++mf)
#pragma unroll
            for (int nf = 0; nf < 3; ++nf)
                acc[mf][nf] = __builtin_amdgcn_mfma_f32_16x16x32_bf16(
                    a[mf], b[nf], acc[mf][nf], 0, 0, 0);
    };

    // ---- K-loop: 8 chunks of 32 ch, double-buffered ----
    xload(0); stageY(0, 0); xwrite(0);
    __syncthreads();
    for (int c = 0; c < 8; ++c) {
        const int b = c & 1;
        if (c < 7) { xload(c + 1); stageY(b ^ 1, c + 1); }  // async: DMA + reg loads
        compute(sbuf[b]);                                    // MFMAs hide x latency
        if (c < 7) xwrite(b ^ 1);                            // pack after compute
        __syncthreads();                                     // drains vmcnt -> next buf ready
    }

    // ---- x2 reduce; init tables (staging buffers dead now) ----
    if (xw) atomicAdd(&x2s[xpix], xsq);
    for (int i = t; i < TBL; i += BLK) table[i] = 0xBF800000u;  // fmap(1.0f)
    __syncthreads();

    // ---- epilogue: d -> sigmoid -> label-masked min ----
    // C layout: col(n) = l&15, row(m) = (l>>4)*4 + reg.
#pragma unroll
    for (int mf = 0; mf < 2; ++mf) {
#pragma unroll
        for (int nf = 0; nf < 3; ++nf) {
#pragma unroll
            for (int r = 0; r < 4; ++r) {
                const int q = mf * 16 + lg * 4 + r;       // dest pixel 0..31
                const int s = wid * 48 + nf * 16 + l15;   // src pixel 0..191
                const int qr = q >> 3, qc = q & 7;
                const int sr = s >> 4, sc = s & 15;
                const int di = sr - qr, dj = sc - qc;
                const int lab = labs[s];
                if (di >= 0 && di <= 2 * MD && dj >= 0 && dj <= 2 * MD &&
                    lab >= 0 && lab < NC) {
                    const float d  = x2s[q] + y2s[s] - 2.0f * acc[mf][nf][r];
                    const float sg = 1.0f / (1.0f + __expf(-d));
                    atomicMin(&table[q * NC + lab], fmap(fmaf(2.0f, sg, -1.0f)));
                }
            }
        }
    }
    __syncthreads();

    // ---- write out[n][class][h0+qr][w0+qc] ----
    const size_t ob = (size_t)n * NC * HW;
    for (int i = t; i < TBL; i += BLK) {
        const int g = i >> 5;        // class
        const int q = i & 31;        // dest pixel
        const int qr = q >> 3, qc = q & 7;
        out[ob + (size_t)g * HW + (size_t)(h0 + qr) * Ww + (w0 + qc)] =
            funmap(table[q * NC + g]);
    }
}

extern "C" void kernel_launch(void* const* d_in, const int* in_sizes, int n_in,
                              void* d_out, int out_size, void* d_ws, size_t ws_size,
                              hipStream_t stream) {
    const float* x      = (const float*)d_in[0];
    const float* y      = (const float*)d_in[1];
    const int*   labels = (const int*)d_in[2];
    float*       out    = (float*)d_out;
    uint4* yT  = (uint4*)d_ws;
    float* y2g = (float*)((char*)d_ws + Y2_OFF);
    (void)in_sizes; (void)n_in; (void)out_size; (void)ws_size;

    hipMemsetAsync(y2g, 0, Y2_BYTES, stream);
    prep_y<<<dim3(PBLK), dim3(256), 0, stream>>>(y, yT, y2g);
    propnet_mfma<<<dim3(NBLK), dim3(BLK), 0, stream>>>(x, yT, y2g, labels, out);
}

// Round 3
// 31.757 us; speedup vs baseline: 1.1742x; 1.1742x over previous
//
#include <hip/hip_runtime.h>
#include <stdint.h>

// PropNet cost-volume via bf16 MFMA. Prepass transposes BOTH x and y to bf16
// [n][cq][pix][8ch] and emits per-pixel sq-norms (no atomics, no memset);
// main kernel's K-loop is pure global_load_lds DMA.
// N=2, C=256, H=W=96, max_distance=4 (window 9x9), num_class=124.
#define Nn 2
#define Cc 256
#define Hh 96
#define Ww 96
#define HW (Hh * Ww)
#define MD 4
#define NC 124
#define TH 4                    // dest tile rows
#define TWD 8                   // dest tile cols
#define NQ (TH * TWD)           // 32 dest pixels (MFMA M)
#define SH (TH + 2 * MD)        // 12 window rows
#define SWD (TWD + 2 * MD)      // 16 window cols
#define NS (SH * SWD)           // 192 src pixels (MFMA N)
#define BLK 256                 // 4 waves
#define NBW (Ww / TWD)          // 12
#define NBH (Hh / TH)           // 24
#define NBLK (Nn * NBH * NBW)   // 576 blocks (divisible by 8)
#define YROW 64                 // bytes per pixel row in a chunk (32 ch * 2B)
#define XOFF (NS * YROW)        // 12288: x region offset inside a buffer
#define BUFSZ (XOFF + NQ * YROW) // 14336 bytes per buffer
#define TBL (NQ * NC)           // 3968 table entries (15872B <= 2*BUFSZ)
#define CQ 32                   // 8-channel groups in C=256

// prepass geometry: block = 32 pixels x all 256 ch x both tensors
#define PPB 32
#define PBLK (Nn * HW / PPB)    // 576 blocks

// workspace layout (bytes)
#define TEN_BYTES ((size_t)Nn * CQ * HW * 16)   // 9.44 MB per tensor
#define XT_OFF  TEN_BYTES
#define Y2_OFF  (TEN_BYTES * 2)
#define X2_OFF  (Y2_OFF + (size_t)Nn * HW * 4)

typedef short short8 __attribute__((ext_vector_type(8)));
typedef float f32x4 __attribute__((ext_vector_type(4)));

// Monotone float -> uint mapping so unsigned min == float min.
__device__ __forceinline__ unsigned fmap(float f) {
    unsigned b = __float_as_uint(f);
    return (b & 0x80000000u) ? ~b : (b | 0x80000000u);
}
__device__ __forceinline__ float funmap(unsigned u) {
    unsigned b = (u & 0x80000000u) ? (u & 0x7fffffffu) : ~u;
    return __uint_as_float(b);
}
// XOR-swizzled byte offset of 16B ch-slot `slot` in pixel-row `row`.
__device__ __forceinline__ int swz(int row, int slot) {
    return row * YROW + ((slot ^ ((row >> 1) & 3)) << 4);
}

// ---------------- prepass: fp32 NCHW -> bf16 [n][cq][pix][8], per-pixel norms
__global__ __launch_bounds__(256) void prep_xy(
    const float* __restrict__ x, const float* __restrict__ y,
    uint4* __restrict__ yT, uint4* __restrict__ xT,
    float* __restrict__ y2g, float* __restrict__ x2g)
{
    __shared__ float red[2][8][PPB];   // [tensor][chan-octant][pixel]
    const int t = threadIdx.x;
    const int bid = blockIdx.x;
    const int n = bid / (HW / PPB);
    const int pix0 = (bid - n * (HW / PPB)) * PPB;
    const int pl  = t & 31;            // pixel lane -> coalesced
    const int grp = t >> 5;            // 0..7
    const size_t pbase = (size_t)n * Cc * HW + pix0 + pl;

    float sq[2] = {0.f, 0.f};
#pragma unroll
    for (int i = 0; i < 8; ++i) {
        const int ts = i >> 2;                 // 0 = y, 1 = x
        const int cq = grp * 4 + (i & 3);      // 0..31
        const float* src = (ts ? x : y) + pbase + (size_t)(cq * 8) * HW;
        float v[8];
#pragma unroll
        for (int j = 0; j < 8; ++j) v[j] = src[(size_t)j * HW];
        float s = 0.f;
        unsigned pk[4];
#pragma unroll
        for (int j = 0; j < 4; ++j) {
            s = fmaf(v[2*j],   v[2*j],   s);
            s = fmaf(v[2*j+1], v[2*j+1], s);
            pk[j] = (__float_as_uint(v[2*j]) >> 16) |
                    (__float_as_uint(v[2*j+1]) & 0xffff0000u);
        }
        sq[ts] += s;
        uint4* dst = (ts ? xT : yT) + ((size_t)n * CQ + cq) * HW + pix0 + pl;
        *dst = make_uint4(pk[0], pk[1], pk[2], pk[3]);
    }
    red[0][grp][pl] = sq[0];
    red[1][grp][pl] = sq[1];
    __syncthreads();
    if (t < 64) {
        const int ts = t >> 5, p = t & 31;
        float s = 0.f;
#pragma unroll
        for (int g = 0; g < 8; ++g) s += red[ts][g][p];
        (ts ? x2g : y2g)[(size_t)n * HW + pix0 + p] = s;
    }
}

// ---------------- main kernel --------------------------------------------
__global__ __launch_bounds__(BLK) void propnet_mfma(
    const uint4* __restrict__ yT, const uint4* __restrict__ xT,
    const float* __restrict__ y2g, const float* __restrict__ x2g,
    const int* __restrict__ labels, float* __restrict__ out)
{
    __shared__ __align__(16) unsigned char sbuf[2][BUFSZ];  // double-buffered staging
    __shared__ float y2s[NS];
    __shared__ float x2s[NQ];
    __shared__ int   labs[NS];
    unsigned* table = (unsigned*)&sbuf[0][0];  // aliased after the K-loop

    const int t = threadIdx.x;

    // XCD-aware bijective swizzle: contiguous 72-block chunk per XCD.
    const int orig = blockIdx.x;
    const int lin  = (orig & 7) * (NBLK / 8) + (orig >> 3);
    const int n    = lin / (NBH * NBW);
    const int rem  = lin - n * (NBH * NBW);
    const int h0   = (rem / NBW) * TH;
    const int w0   = (rem % NBW) * TWD;

    if (t < NS) {
        const int sr = t >> 4, sc = t & 15;
        const int gh = h0 - MD + sr, gw = w0 - MD + sc;
        const bool ok = (gh >= 0) && (gh < Hh) && (gw >= 0) && (gw < Ww);
        labs[t] = ok ? labels[(size_t)n * HW + gh * Ww + gw] : -1;  // -1: excluded
        y2s[t]  = ok ? y2g[(size_t)n * HW + gh * Ww + gw] : 0.f;
    }
    if (t < NQ) {
        const int qr = t >> 3, qc = t & 7;
        x2s[t] = x2g[(size_t)n * HW + (size_t)(h0 + qr) * Ww + (w0 + qc)];
    }

    const int lane = t & 63;
    const int wid  = t >> 6;

    // ---- y DMA: 3 insts/wave/chunk; linear LDS dest, swizzle realized by
    // permuting the per-lane GLOBAL source (rule #21).
    size_t ysrc[3]; int yl[3];
    {
        const int sc4 = lane >> 2;                 // pixel col within 16-group
        const int pos = lane & 3;                  // 16B position in pixel row
        const int cqw = pos ^ ((sc4 >> 1) & 3);    // ch-slot stored at this pos
#pragma unroll
        for (int i = 0; i < 3; ++i) {
            const int g  = wid * 3 + i;            // window row 0..11
            const int gh = min(max(h0 - MD + g, 0), Hh - 1);   // clamp; excluded by labs
            const int gw = min(max(w0 - MD + sc4, 0), Ww - 1);
            ysrc[i] = (size_t)cqw * HW + (size_t)gh * Ww + gw;
            yl[i]   = g * 1024;                    // 16 pixels * 64B
        }
    }
    // ---- x DMA: 1 inst each on waves 0,1 (2KB region).
    const bool hasx = (wid < 2);
    size_t xsrc = 0; int xl = 0;
    if (hasx) {
        const int q   = wid * 16 + (lane >> 2);    // dest pixel 0..31
        const int pos = lane & 3;
        const int s   = pos ^ ((q >> 1) & 3);      // slot stored at this pos
        xsrc = (size_t)s * HW + (size_t)(h0 + (q >> 3)) * Ww + (w0 + (q & 7));
        xl   = XOFF + wid * 1024;
    }
    const uint4* yTn = yT + (size_t)n * CQ * HW;
    const uint4* xTn = xT + (size_t)n * CQ * HW;
    auto stage = [&](int b, int c) {
        const uint4* yb = yTn + (size_t)(c * 4) * HW;
#pragma unroll
        for (int i = 0; i < 3; ++i)
            __builtin_amdgcn_global_load_lds(
                (const __attribute__((address_space(1))) unsigned int*)(yb + ysrc[i]),
                (__attribute__((address_space(3))) unsigned int*)(sbuf[b] + yl[i]),
                16, 0, 0);
        if (hasx)
            __builtin_amdgcn_global_load_lds(
                (const __attribute__((address_space(1))) unsigned int*)
                    (xTn + (size_t)(c * 4) * HW + xsrc),
                (__attribute__((address_space(3))) unsigned int*)(sbuf[b] + xl),
                16, 0, 0);
    };

    // ---- MFMA fragments ----
    const int l15 = lane & 15;
    const int lg  = lane >> 4;        // 8-ch k-slot
    int aoff[2], boff[3];
#pragma unroll
    for (int mf = 0; mf < 2; ++mf) aoff[mf] = XOFF + swz(mf * 16 + l15, lg);
#pragma unroll
    for (int nf = 0; nf < 3; ++nf) boff[nf] = swz(wid * 48 + nf * 16 + l15, lg);

    f32x4 acc[2][3];
#pragma unroll
    for (int mf = 0; mf < 2; ++mf)
#pragma unroll
        for (int nf = 0; nf < 3; ++nf)
            acc[mf][nf] = (f32x4){0.f, 0.f, 0.f, 0.f};

    auto compute = [&](const unsigned char* bb) {
        short8 a[2], b[3];
#pragma unroll
        for (int mf = 0; mf < 2; ++mf) a[mf] = *(const short8*)(bb + aoff[mf]);
#pragma unroll
        for (int nf = 0; nf < 3; ++nf) b[nf] = *(const short8*)(bb + boff[nf]);
#pragma unroll
        for (int mf = 0; mf < 2; ++mf)
#pragma unroll
            for (int nf = 0; nf < 3; ++nf)
                acc[mf][nf] = __builtin_amdgcn_mfma_f32_16x16x32_bf16(
                    a[mf], b[nf], acc[mf][nf], 0, 0, 0);
    };

    // ---- K-loop: 8 chunks of 32 ch, double-buffered, pure DMA staging ----
    stage(0, 0);
    __syncthreads();
    for (int c = 0; c < 8; ++c) {
        const int b = c & 1;
        if (c < 7) stage(b ^ 1, c + 1);   // next-chunk DMA flies over MFMAs
        compute(sbuf[b]);
        __syncthreads();                   // drains vmcnt -> next buf ready
    }

    // ---- init tables (staging buffers dead now) ----
    for (int i = t; i < TBL; i += BLK) table[i] = 0xBF800000u;  // fmap(1.0f)
    __syncthreads();

    // ---- epilogue: d -> sigmoid -> label-masked min ----
    // C layout: col(n) = l&15, row(m) = (l>>4)*4 + reg.
#pragma unroll
    for (int mf = 0; mf < 2; ++mf) {
#pragma unroll
        for (int nf = 0; nf < 3; ++nf) {
#pragma unroll
            for (int r = 0; r < 4; ++r) {
                const int q = mf * 16 + lg * 4 + r;       // dest pixel 0..31
                const int s = wid * 48 + nf * 16 + l15;   // src pixel 0..191
                const int qr = q >> 3, qc = q & 7;
                const int sr = s >> 4, sc = s & 15;
                const int di = sr - qr, dj = sc - qc;
                const int lab = labs[s];
                if (di >= 0 && di <= 2 * MD && dj >= 0 && dj <= 2 * MD &&
                    lab >= 0 && lab < NC) {
                    const float d  = x2s[q] + y2s[s] - 2.0f * acc[mf][nf][r];
                    const float sg = 1.0f / (1.0f + __expf(-d));
                    atomicMin(&table[q * NC + lab], fmap(fmaf(2.0f, sg, -1.0f)));
                }
            }
        }
    }
    __syncthreads();

    // ---- write out[n][class][h0+qr][w0+qc] ----
    const size_t ob = (size_t)n * NC * HW;
    for (int i = t; i < TBL; i += BLK) {
        const int g = i >> 5;        // class
        const int q = i & 31;        // dest pixel
        const int qr = q >> 3, qc = q & 7;
        out[ob + (size_t)g * HW + (size_t)(h0 + qr) * Ww + (w0 + qc)] =
            funmap(table[q * NC + g]);
    }
}

extern "C" void kernel_launch(void* const* d_in, const int* in_sizes, int n_in,
                              void* d_out, int out_size, void* d_ws, size_t ws_size,
                              hipStream_t stream) {
    const float* x      = (const float*)d_in[0];
    const float* y      = (const float*)d_in[1];
    const int*   labels = (const int*)d_in[2];
    float*       out    = (float*)d_out;
    uint4* yT  = (uint4*)d_ws;
    uint4* xT  = (uint4*)((char*)d_ws + XT_OFF);
    float* y2g = (float*)((char*)d_ws + Y2_OFF);
    float* x2g = (float*)((char*)d_ws + X2_OFF);
    (void)in_sizes; (void)n_in; (void)out_size; (void)ws_size;

    prep_xy<<<dim3(PBLK), dim3(256), 0, stream>>>(x, y, yT, xT, y2g, x2g);
    propnet_mfma<<<dim3(NBLK), dim3(BLK), 0, stream>>>(yT, xT, y2g, x2g, labels, out);
}

// Round 4
// 30.842 us; speedup vs baseline: 1.2091x; 1.0297x over previous
//
#include <hip/hip_runtime.h>
#include <stdint.h>

// PropNet cost-volume via bf16 MFMA. Prepass transposes y to bf16
// [n][cq][pix][8ch] (float4-coalesced loads -> LDS -> pack) and emits exact
// fp32 per-pixel y-norms (no atomics, no memset). Main kernel DMA-stages y,
// reg-stages x (read once, hidden under MFMAs).
// N=2, C=256, H=W=96, max_distance=4 (window 9x9), num_class=124.
#define Nn 2
#define Cc 256
#define Hh 96
#define Ww 96
#define HW (Hh * Ww)
#define MD 4
#define NC 124
#define TH 4                    // dest tile rows
#define TWD 8                   // dest tile cols
#define NQ (TH * TWD)           // 32 dest pixels (MFMA M)
#define SH (TH + 2 * MD)        // 12 window rows
#define SWD (TWD + 2 * MD)      // 16 window cols
#define NS (SH * SWD)           // 192 src pixels (MFMA N)
#define BLK 256                 // 4 waves
#define NBW (Ww / TWD)          // 12
#define NBH (Hh / TH)           // 24
#define NBLK (Nn * NBH * NBW)   // 576 blocks (divisible by 8)
#define YROW 64                 // bytes per pixel row in a chunk (32 ch * 2B)
#define XOFF (NS * YROW)        // 12288: x region offset inside a buffer
#define BUFSZ (XOFF + NQ * YROW) // 14336 bytes per buffer
#define TBL (NQ * NC)           // 3968 table entries (15872B <= 2*BUFSZ)
#define CQ 32                   // 8-channel groups in C=256

// prepass geometry: block = 32 pixels x all 256 channels of y
#define PPB 32
#define PBLK (Nn * HW / PPB)    // 576 blocks
#define TSTR 40                 // LDS words per channel row (16B-aligned, 2-way banks)

// workspace layout (bytes)
#define TEN_BYTES ((size_t)Nn * CQ * HW * 16)   // 9.44 MB (yT)
#define Y2_OFF  TEN_BYTES

typedef short short8 __attribute__((ext_vector_type(8)));
typedef float f32x4 __attribute__((ext_vector_type(4)));

// Monotone float -> uint mapping so unsigned min == float min.
__device__ __forceinline__ unsigned fmap(float f) {
    unsigned b = __float_as_uint(f);
    return (b & 0x80000000u) ? ~b : (b | 0x80000000u);
}
__device__ __forceinline__ float funmap(unsigned u) {
    unsigned b = (u & 0x80000000u) ? (u & 0x7fffffffu) : ~u;
    return __uint_as_float(b);
}
// XOR-swizzled byte offset of 16B ch-slot `slot` in pixel-row `row`.
__device__ __forceinline__ int swz(int row, int slot) {
    return row * YROW + ((slot ^ ((row >> 1) & 3)) << 4);
}

// ---------------- prepass: y fp32 NCHW -> bf16 [n][cq][pix][8], y2 ----------
__global__ __launch_bounds__(256) void prep_y(
    const float* __restrict__ y, uint4* __restrict__ yT, float* __restrict__ y2g)
{
    __shared__ float tile[Cc * TSTR];   // 40 KB fp32 staging
    __shared__ float red[8][PPB];
    const int t = threadIdx.x;
    const int bid = blockIdx.x;
    const int n = bid / (HW / PPB);
    const int pix0 = (bid - n * (HW / PPB)) * PPB;
    const float* src = y + (size_t)n * Cc * HW + pix0;

    // 8 independent float4 loads/thread, fully coalesced (wave = 2 ch x 128B).
#pragma unroll
    for (int k = 0; k < 8; ++k) {
        const int task = t + 256 * k;
        const int ch = task >> 3;
        const int ck = task & 7;            // 4-pixel chunk within the 32
        const float4 v = *(const float4*)(src + (size_t)ch * HW + ck * 4);
        *(float4*)&tile[ch * TSTR + ck * 4] = v;
    }
    __syncthreads();

    // pack: thread owns pixel (t&31), cq slices {t>>5 + 8k}.
    const int pix = t & 31;
    const int g0  = t >> 5;
    float sq = 0.f;
#pragma unroll
    for (int k = 0; k < 4; ++k) {
        const int cq = g0 + 8 * k;
        float v[8];
#pragma unroll
        for (int j = 0; j < 8; ++j) v[j] = tile[(cq * 8 + j) * TSTR + pix];
        unsigned pk[4];
#pragma unroll
        for (int j = 0; j < 4; ++j) {
            sq = fmaf(v[2*j],   v[2*j],   sq);
            sq = fmaf(v[2*j+1], v[2*j+1], sq);
            pk[j] = (__float_as_uint(v[2*j]) >> 16) |
                    (__float_as_uint(v[2*j+1]) & 0xffff0000u);
        }
        yT[((size_t)n * CQ + cq) * HW + pix0 + pix] =
            make_uint4(pk[0], pk[1], pk[2], pk[3]);
    }
    red[g0][pix] = sq;
    __syncthreads();
    if (t < PPB) {
        float s = 0.f;
#pragma unroll
        for (int g = 0; g < 8; ++g) s += red[g][t];
        y2g[(size_t)n * HW + pix0 + t] = s;
    }
}

// ---------------- main kernel --------------------------------------------
__global__ __launch_bounds__(BLK) void propnet_mfma(
    const float* __restrict__ x, const uint4* __restrict__ yT,
    const float* __restrict__ y2g, const int* __restrict__ labels,
    float* __restrict__ out)
{
    __shared__ __align__(16) unsigned char sbuf[2][BUFSZ];  // double-buffered staging
    __shared__ float y2s[NS];
    __shared__ float x2s[NQ];
    __shared__ int   labs[NS];
    unsigned* table = (unsigned*)&sbuf[0][0];  // aliased after the K-loop

    const int t = threadIdx.x;

    // XCD-aware bijective swizzle: contiguous 72-block chunk per XCD.
    const int orig = blockIdx.x;
    const int lin  = (orig & 7) * (NBLK / 8) + (orig >> 3);
    const int n    = lin / (NBH * NBW);
    const int rem  = lin - n * (NBH * NBW);
    const int h0   = (rem / NBW) * TH;
    const int w0   = (rem % NBW) * TWD;

    if (t < NS) {
        const int sr = t >> 4, sc = t & 15;
        const int gh = h0 - MD + sr, gw = w0 - MD + sc;
        const bool ok = (gh >= 0) && (gh < Hh) && (gw >= 0) && (gw < Ww);
        labs[t] = ok ? labels[(size_t)n * HW + gh * Ww + gw] : -1;  // -1: excluded
        y2s[t]  = ok ? y2g[(size_t)n * HW + gh * Ww + gw] : 0.f;
    }
    if (t < NQ) x2s[t] = 0.f;

    const int lane = t & 63;
    const int wid  = t >> 6;

    // ---- y DMA: 3 insts/wave/chunk; linear LDS dest, swizzle realized by
    // permuting the per-lane GLOBAL source (rule #21).
    size_t ysrc[3]; int yl[3];
    {
        const int sc4 = lane >> 2;                 // pixel col within 16-group
        const int pos = lane & 3;                  // 16B position in pixel row
        const int cqw = pos ^ ((sc4 >> 1) & 3);    // ch-slot stored at this pos
#pragma unroll
        for (int i = 0; i < 3; ++i) {
            const int g  = wid * 3 + i;            // window row 0..11
            const int gh = min(max(h0 - MD + g, 0), Hh - 1);   // clamp; excluded by labs
            const int gw = min(max(w0 - MD + sc4, 0), Ww - 1);
            ysrc[i] = (size_t)cqw * HW + (size_t)gh * Ww + gw;
            yl[i]   = g * 1024;                    // 16 pixels * 64B
        }
    }
    const uint4* yTn = yT + (size_t)n * CQ * HW;
    auto stageY = [&](int b, int c) {
        const uint4* yb = yTn + (size_t)(c * 4) * HW;
#pragma unroll
        for (int i = 0; i < 3; ++i)
            __builtin_amdgcn_global_load_lds(
                (const __attribute__((address_space(1))) unsigned int*)(yb + ysrc[i]),
                (__attribute__((address_space(3))) unsigned int*)(sbuf[b] + yl[i]),
                16, 0, 0);
    };

    // ---- x path: reg-staged fp32 (read once, no overlap tax); T14 split.
    const bool xw = (t < 128);
    const float* xptr = x; int xoffw = 0, xpix = 0;
    if (xw) {
        xpix = t & 31;
        const int grp = t >> 5;
        const int qr = xpix >> 3, qc = xpix & 7;
        xptr = x + ((size_t)n * Cc + grp * 8) * HW + (size_t)(h0 + qr) * Ww + (w0 + qc);
        xoffw = XOFF + swz(xpix, grp);
    }
    float xsq = 0.f;
    float xv[8];
    auto xload = [&](int c) {
        if (!xw) return;
        const float* p = xptr + (size_t)(c * 32) * HW;
#pragma unroll
        for (int j = 0; j < 8; ++j) xv[j] = p[(size_t)j * HW];
    };
    auto xwrite = [&](int b) {
        if (!xw) return;
        unsigned pk[4];
#pragma unroll
        for (int j = 0; j < 4; ++j) {
            xsq = fmaf(xv[2*j],   xv[2*j],   xsq);
            xsq = fmaf(xv[2*j+1], xv[2*j+1], xsq);
            pk[j] = (__float_as_uint(xv[2*j]) >> 16) |
                    (__float_as_uint(xv[2*j+1]) & 0xffff0000u);
        }
        *(uint4*)(sbuf[b] + xoffw) = make_uint4(pk[0], pk[1], pk[2], pk[3]);
    };

    // ---- MFMA fragments ----
    const int l15 = lane & 15;
    const int lg  = lane >> 4;        // 8-ch k-slot
    int aoff[2], boff[3];
#pragma unroll
    for (int mf = 0; mf < 2; ++mf) aoff[mf] = XOFF + swz(mf * 16 + l15, lg);
#pragma unroll
    for (int nf = 0; nf < 3; ++nf) boff[nf] = swz(wid * 48 + nf * 16 + l15, lg);

    f32x4 acc[2][3];
#pragma unroll
    for (int mf = 0; mf < 2; ++mf)
#pragma unroll
        for (int nf = 0; nf < 3; ++nf)
            acc[mf][nf] = (f32x4){0.f, 0.f, 0.f, 0.f};

    auto compute = [&](const unsigned char* bb) {
        short8 a[2], b[3];
#pragma unroll
        for (int mf = 0; mf < 2; ++mf) a[mf] = *(const short8*)(bb + aoff[mf]);
#pragma unroll
        for (int nf = 0; nf < 3; ++nf) b[nf] = *(const short8*)(bb + boff[nf]);
#pragma unroll
        for (int mf = 0; mf < 2; ++mf)
#pragma unroll
            for (int nf = 0; nf < 3; ++nf)
                acc[mf][nf] = __builtin_amdgcn_mfma_f32_16x16x32_bf16(
                    a[mf], b[nf], acc[mf][nf], 0, 0, 0);
    };

    // ---- K-loop: 8 chunks of 32 ch, double-buffered ----
    xload(0); stageY(0, 0); xwrite(0);
    __syncthreads();
    for (int c = 0; c < 8; ++c) {
        const int b = c & 1;
        if (c < 7) { xload(c + 1); stageY(b ^ 1, c + 1); }  // async over MFMAs
        compute(sbuf[b]);
        if (c < 7) xwrite(b ^ 1);                            // pack after compute
        __syncthreads();                                     // drains vmcnt
    }

    // ---- x2 reduce; init tables (staging buffers dead now) ----
    if (xw) atomicAdd(&x2s[xpix], xsq);
    for (int i = t; i < TBL; i += BLK) table[i] = 0xBF800000u;  // fmap(1.0f)
    __syncthreads();

    // ---- epilogue: d -> sigmoid -> label-masked min ----
    // C layout: col(n) = l&15, row(m) = (l>>4)*4 + reg.
#pragma unroll
    for (int mf = 0; mf < 2; ++mf) {
#pragma unroll
        for (int nf = 0; nf < 3; ++nf) {
#pragma unroll
            for (int r = 0; r < 4; ++r) {
                const int q = mf * 16 + lg * 4 + r;       // dest pixel 0..31
                const int s = wid * 48 + nf * 16 + l15;   // src pixel 0..191
                const int qr = q >> 3, qc = q & 7;
                const int sr = s >> 4, sc = s & 15;
                const int di = sr - qr, dj = sc - qc;
                const int lab = labs[s];
                if (di >= 0 && di <= 2 * MD && dj >= 0 && dj <= 2 * MD &&
                    lab >= 0 && lab < NC) {
                    const float d  = x2s[q] + y2s[s] - 2.0f * acc[mf][nf][r];
                    const float sg = 1.0f / (1.0f + __expf(-d));
                    atomicMin(&table[q * NC + lab], fmap(fmaf(2.0f, sg, -1.0f)));
                }
            }
        }
    }
    __syncthreads();

    // ---- write out[n][class][h0+qr][w0+qc] ----
    const size_t ob = (size_t)n * NC * HW;
    for (int i = t; i < TBL; i += BLK) {
        const int g = i >> 5;        // class
        const int q = i & 31;        // dest pixel
        const int qr = q >> 3, qc = q & 7;
        out[ob + (size_t)g * HW + (size_t)(h0 + qr) * Ww + (w0 + qc)] =
            funmap(table[q * NC + g]);
    }
}

extern "C" void kernel_launch(void* const* d_in, const int* in_sizes, int n_in,
                              void* d_out, int out_size, void* d_ws, size_t ws_size,
                              hipStream_t stream) {
    const float* x      = (const float*)d_in[0];
    const float* y      = (const float*)d_in[1];
    const int*   labels = (const int*)d_in[2];
    float*       out    = (float*)d_out;
    uint4* yT  = (uint4*)d_ws;
    float* y2g = (float*)((char*)d_ws + Y2_OFF);
    (void)in_sizes; (void)n_in; (void)out_size; (void)ws_size;

    prep_y<<<dim3(PBLK), dim3(256), 0, stream>>>(y, yT, y2g);
    propnet_mfma<<<dim3(NBLK), dim3(BLK), 0, stream>>>(x, yT, y2g, labels, out);
}